// Round 1
// baseline (5675.756 us; speedup 1.0000x reference)
//
#include <hip/hip_runtime.h>
#include <stdint.h>

typedef unsigned short u16;
typedef unsigned int u32;
typedef __attribute__((ext_vector_type(8))) short short8;
typedef __attribute__((ext_vector_type(8))) u16 u16x8;
typedef __attribute__((ext_vector_type(4))) float f32x4;
typedef __attribute__((ext_vector_type(2))) u32 u32x2;

#define DEVINL static __device__ __forceinline__

#if !__has_builtin(__builtin_amdgcn_exp2f)
#define __builtin_amdgcn_exp2f(x) exp2f(x)
#endif
#if !__has_builtin(__builtin_amdgcn_rcpf)
#define __builtin_amdgcn_rcpf(x) (1.0f/(x))
#endif

#define MFMA16(a, b, c) __builtin_amdgcn_mfma_f32_16x16x32_bf16((a), (b), (c), 0, 0, 0)

constexpr float LOG2E_C    = 1.4426950408889634f;
constexpr float TWOLOG2E_C = 2.8853900817779268f;
constexpr float RSCALE_LG  = 1.4426950408889634f / 11.313708498984761f; // log2e / sqrt(128)

// ---------------- workspace layout (bytes) ----------------
constexpr size_t A256(size_t x){ return (x + 255) & ~(size_t)255; }
constexpr size_t OFS_EMB   = 0;                                         // u16 [8][2051][128] unmasked emb
constexpr size_t OFS_PAD   = A256(OFS_EMB  + (size_t)8*2051*128*2);     // u16 [8][2048][128] masked
constexpr size_t OFS_X1    = A256(OFS_PAD  + (size_t)8*2048*128*2);     // u16 [8][2050][128]
constexpr size_t OFS_X2    = A256(OFS_X1   + (size_t)8*2050*128*2);     // u16 [8][2049][128]
constexpr size_t OFS_QKVW  = A256(OFS_X2   + (size_t)8*2049*128*2);     // u16 [3][256][128] folded
constexpr size_t OFS_WA2   = A256(OFS_QKVW + (size_t)3*256*128*2);      // u16 [256][256]
constexpr size_t OFS_CONVW = A256(OFS_WA2  + (size_t)256*256*2);        // u16 [3][128][256]
constexpr size_t OFS_WIH0  = A256(OFS_CONVW+ (size_t)3*128*256*2);      // u16 [2][384][128]
constexpr size_t OFS_WIH1  = A256(OFS_WIH0 + (size_t)2*384*128*2);      // u16 [2][384][256]
constexpr size_t OFS_BIASX = A256(OFS_WIH1 + (size_t)2*384*256*2);      // f32 [2][2][384] scaled biases
constexpr size_t OFS_BHHN  = A256(OFS_BIASX+ (size_t)2*2*384*4);        // f32 [2][2][128] 2log2e*bhh_n
constexpr size_t OFS_Q     = A256(OFS_BHHN + (size_t)2*2*128*4);        // u16 [8][2048][256]
constexpr size_t OFS_K     = A256(OFS_Q    + (size_t)8*2048*256*2);
constexpr size_t OFS_V     = A256(OFS_K    + (size_t)8*2048*256*2);
constexpr size_t OFS_CS    = A256(OFS_V    + (size_t)8*2048*256*2);     // f32 [8][2048] colsum
constexpr size_t OFS_TM    = A256(OFS_CS   + (size_t)8*2048*4);         // f32 [8][128] tmean sums
constexpr size_t OFS_XG    = A256(OFS_TM   + (size_t)8*128*4);          // f32 [2][2048][8][384]
constexpr size_t OFS_H1    = A256(OFS_XG   + (size_t)2*2048*8*384*4);   // u16 [8][2048][256]
constexpr size_t OFS_ENC   = A256(OFS_H1   + (size_t)8*2048*256*2);     // u16 [8][2048][256]
constexpr size_t OFS_ENCW  = A256(OFS_ENC  + (size_t)8*2048*256*2);     // f32 [8][2048][256]
constexpr size_t OFS_SA    = A256(OFS_ENCW + (size_t)8*2048*256*4);     // f32 [8][256]
constexpr size_t OFS_RES   = A256(OFS_SA   + (size_t)8*256*4);          // f32 [8][2][2048]
constexpr size_t OFS_DV    = A256(OFS_RES  + (size_t)8*2*2048*4);       // f32 [8][2][256]

// ---------------- helpers ----------------
DEVINL u16 f2bf(float f){
  u32 u = __builtin_bit_cast(u32, f);
  u32 r = (u + 0x7FFFu + ((u >> 16) & 1u)) >> 16;
  return (u16)r;
}
DEVINL float bf2f(u16 s){ return __builtin_bit_cast(float, (u32)s << 16); }

DEVINL short8 ld8cvt(const float* p, float sc){
  short8 o;
#pragma unroll
  for (int e = 0; e < 8; ++e) o[e] = (short)f2bf(p[e]*sc);
  return o;
}

DEVINL float selpack(float v0, float v1, int hi){
  float v1s = __shfl_xor(v1, 8);   // value from lane l^8
  return hi ? v1s : v0;
}

// ---------------- prep: gathers, weight conversions, zeroing ----------------
__global__ __launch_bounds__(256) void k_prep(
    const int* tok, const int* lens, const float* embed,
    const float* wih0, const float* wih1,
    const float* bih0, const float* bhh0, const float* bih1, const float* bhh1,
    const float* convw, const float* WaW, const float* Qw, const float* Kw, const float* Vw,
    char* ws)
{
  u16* emb_bf   = (u16*)(ws + OFS_EMB);
  u16* pad_bf   = (u16*)(ws + OFS_PAD);
  u16* qkvw     = (u16*)(ws + OFS_QKVW);
  u16* wa2      = (u16*)(ws + OFS_WA2);
  u16* convw_bf = (u16*)(ws + OFS_CONVW);
  u16* wih0_bf  = (u16*)(ws + OFS_WIH0);
  u16* wih1_bf  = (u16*)(ws + OFS_WIH1);
  float* biasx  = (float*)(ws + OFS_BIASX);
  float* bhhn   = (float*)(ws + OFS_BHHN);
  float* colsum = (float*)(ws + OFS_CS);
  float* tmean  = (float*)(ws + OFS_TM);
  const int S0 = 8*2051*128, S1 = 8*2048*128, S2 = 3*256*128, S3 = 256*256, S4 = 3*128*256;
  const int S5 = 2*384*128, S6 = 2*384*256, S7 = 2*2*384 + 2*2*128, S8 = 8*2048 + 8*128;
  const int TOT = S0+S1+S2+S3+S4+S5+S6+S7+S8;
  for (int i = blockIdx.x*256 + threadIdx.x; i < TOT; i += gridDim.x*256){
    int j = i;
    if (j < S0){
      int b = j / (2051*128); int r = j - b*(2051*128); int t = r >> 7, dd = r & 127;
      emb_bf[j] = f2bf(embed[(size_t)tok[b*4000 + t]*128 + dd]);
      continue;
    }
    j -= S0;
    if (j < S1){
      int b = j >> 18; int r = j & 262143; int t = r >> 7, dd = r & 127;
      float v = (t < lens[b]) ? embed[(size_t)tok[b*4000 + t]*128 + dd] : 0.f;
      pad_bf[j] = f2bf(v); continue;
    }
    j -= S1;
    if (j < S2){
      int z = j >> 15; int r = j & 32767; int o = r >> 7, k2 = r & 127;
      const float* W = (z == 0) ? Qw : (z == 1) ? Kw : Vw;
      qkvw[j] = f2bf(W[o*256 + k2] + W[o*256 + 128 + k2]); continue;
    }
    j -= S2;
    if (j < S3){ int h = j >> 8, k2 = j & 255; wa2[j] = f2bf(WaW[(size_t)h*512 + 256 + k2]); continue; }
    j -= S3;
    if (j < S4){
      int ly = j >> 15; int r = j & 32767; int o = r >> 8, k2 = r & 255;
      int i2 = k2 & 127, kap = k2 >> 7;
      convw_bf[j] = f2bf(convw[((size_t)(ly*128 + o)*128 + i2)*2 + kap]); continue;
    }
    j -= S4;
    if (j < S5){ wih0_bf[j] = f2bf(wih0[j]); continue; }
    j -= S5;
    if (j < S6){ wih1_bf[j] = f2bf(wih1[j]); continue; }
    j -= S6;
    if (j < S7){
      if (j < 1536){
        int ly = j / 768; int r = j - ly*768; int d = r / 384, g = r % 384;
        float bi = (ly ? bih1 : bih0)[d*384 + g];
        float bh = (ly ? bhh1 : bhh0)[d*384 + g];
        biasx[j] = (g < 256) ? (-LOG2E_C*(bi + bh)) : (TWOLOG2E_C*bi);
      } else {
        int j2 = j - 1536; int ly = j2 >> 8; int r = j2 & 255; int d = r >> 7, jj = r & 127;
        bhhn[j2] = TWOLOG2E_C*((ly ? bhh1 : bhh0)[d*384 + 256 + jj]);
      }
      continue;
    }
    j -= S7;
    if (j < 8*2048) colsum[j] = 0.f; else tmean[j - 8*2048] = 0.f;
  }
}

// ---------------- conv1d (k=2, VALID) as im2col MFMA; layer 2 accumulates tmean ----------------
template<int LIN, int LOUT, int LAYER>
__global__ __launch_bounds__(256, 1) void k_conv(const int* lens, const float* convb, char* ws){
  const int tt = blockIdx.x, b = blockIdx.y;
  const u16* in = (LAYER == 0) ? (const u16*)(ws + OFS_EMB)
                : (LAYER == 1) ? (const u16*)(ws + OFS_X1) : (const u16*)(ws + OFS_X2);
  u16* out = (LAYER == 0) ? (u16*)(ws + OFS_X1) : (u16*)(ws + OFS_X2);
  const u16* wmat = (const u16*)(ws + OFS_CONVW) + (size_t)LAYER*128*256;
  float* tmean = (float*)(ws + OFS_TM);
  __shared__ __align__(16) u16 sA[65][136];
  const int tid = threadIdx.x, w = tid >> 6, l = tid & 63, rowg = l >> 4, cl = l & 15;
  for (int idx = tid; idx < 65*16; idx += 256){
    int row = idx >> 4, chn = idx & 15;
    int t = tt*64 + row;
    u16x8 v = {0,0,0,0,0,0,0,0};
    if (t < LIN) v = *(const u16x8*)(in + ((size_t)(b*LIN + t))*128 + chn*8);
    *(u16x8*)&sA[row][chn*8] = v;
  }
  __syncthreads();
  f32x4 acc[8];
#pragma unroll
  for (int nt = 0; nt < 8; ++nt) acc[nt] = f32x4{0.f,0.f,0.f,0.f};
#pragma unroll
  for (int kk = 0; kk < 8; ++kk){
    const int rofs = (kk >= 4) ? 1 : 0;
    short8 a = *(const short8*)&sA[w*16 + cl + rofs][(kk & 3)*32 + rowg*8];
#pragma unroll
    for (int nt = 0; nt < 8; ++nt){
      short8 bb = *(const short8*)(wmat + (size_t)(nt*16 + cl)*256 + kk*32 + rowg*8);
      acc[nt] = MFMA16(a, bb, acc[nt]);
    }
  }
  if (LAYER < 2){
#pragma unroll
    for (int nt = 0; nt < 8; ++nt){
      int o = nt*16 + cl;
      float bias = convb[LAYER*128 + o];
#pragma unroll
      for (int r = 0; r < 4; ++r){
        int t = tt*64 + w*16 + rowg*4 + r;
        if (t < LOUT) out[((size_t)(b*LOUT + t))*128 + o] = f2bf(fmaxf(acc[nt][r] + bias, 0.f));
      }
    }
  } else {
    const int lenb = lens[b];
#pragma unroll
    for (int nt = 0; nt < 8; ++nt){
      int o = nt*16 + cl;
      float bias = convb[2*128 + o];
      float s = 0.f;
#pragma unroll
      for (int r = 0; r < 4; ++r){
        int t = tt*64 + w*16 + rowg*4 + r;
        if (t < lenb) s += fmaxf(acc[nt][r] + bias, 0.f);
      }
      s += __shfl_xor(s, 16); s += __shfl_xor(s, 32);
      if (l < 16) atomicAdd(&tmean[b*128 + o], s);
    }
  }
}

// ---------------- Q/K/V = pad_bf @ folded-weight^T ----------------
__global__ __launch_bounds__(256, 1) void k_qkv(char* ws){
  const int tt = blockIdx.x, b = blockIdx.y, z = blockIdx.z;
  const u16* in = (const u16*)(ws + OFS_PAD);
  const u16* wmat = (const u16*)(ws + OFS_QKVW) + (size_t)z*256*128;
  u16* out = (u16*)(ws + ((z == 0) ? OFS_Q : (z == 1) ? OFS_K : OFS_V));
  __shared__ __align__(16) u16 sA[64][136];
  const int tid = threadIdx.x, w = tid >> 6, l = tid & 63, rowg = l >> 4, cl = l & 15;
  for (int idx = tid; idx < 64*16; idx += 256){
    int row = idx >> 4, chn = idx & 15;
    int t = tt*64 + row;
    *(u16x8*)&sA[row][chn*8] = *(const u16x8*)(in + ((size_t)(b*2048 + t))*128 + chn*8);
  }
  __syncthreads();
  f32x4 acc[16];
#pragma unroll
  for (int nt = 0; nt < 16; ++nt) acc[nt] = f32x4{0.f,0.f,0.f,0.f};
#pragma unroll
  for (int kk = 0; kk < 4; ++kk){
    short8 a = *(const short8*)&sA[w*16 + cl][kk*32 + rowg*8];
#pragma unroll
    for (int nt = 0; nt < 16; ++nt){
      short8 bb = *(const short8*)(wmat + (size_t)(nt*16 + cl)*128 + kk*32 + rowg*8);
      acc[nt] = MFMA16(a, bb, acc[nt]);
    }
  }
#pragma unroll
  for (int nt = 0; nt < 16; ++nt){
    int o = nt*16 + cl;
#pragma unroll
    for (int r = 0; r < 4; ++r){
      int t = tt*64 + w*16 + rowg*4 + r;
      out[((size_t)(b*2048 + t))*256 + o] = f2bf(acc[nt][r]);
    }
  }
}

// ---------------- scores: softmax over batch axis, accumulate colsum[b][k] ----------------
__global__ __launch_bounds__(256, 1) void k_scores(const int* lens, char* ws){
  const int kt = blockIdx.x, qt = blockIdx.y;
  const u16* Qp = (const u16*)(ws + OFS_Q);
  const u16* Kp = (const u16*)(ws + OFS_K);
  float* colsum = (float*)(ws + OFS_CS);
  __shared__ __align__(16) u16 sQ[64][264];
  __shared__ __align__(16) u16 sK[64][264];
  __shared__ float cbuf[8][64];
  const int tid = threadIdx.x, w = tid >> 6, l = tid & 63, rowg = l >> 4, cl = l & 15;
  for (int i = tid; i < 512; i += 256) cbuf[i >> 6][i & 63] = 0.f;
  f32x4 c[8][4];
#pragma unroll
  for (int b = 0; b < 8; ++b)
#pragma unroll
    for (int nt = 0; nt < 4; ++nt) c[b][nt] = f32x4{0.f,0.f,0.f,0.f};
#pragma unroll
  for (int b = 0; b < 8; ++b){
    __syncthreads();
    for (int idx = tid; idx < 4096; idx += 256){
      int which = idx >> 11, row = (idx >> 5) & 63, ch = idx & 31;
      if (which){
        *(u16x8*)&sK[row][ch*8] = *(const u16x8*)(Kp + ((size_t)(b*2048 + kt*64 + row))*256 + ch*8);
      } else {
        *(u16x8*)&sQ[row][ch*8] = *(const u16x8*)(Qp + ((size_t)(b*2048 + qt*64 + row))*256 + ch*8);
      }
    }
    __syncthreads();
#pragma unroll
    for (int kk = 0; kk < 8; ++kk){
      short8 a = *(const short8*)&sQ[w*16 + cl][kk*32 + rowg*8];
#pragma unroll
      for (int nt = 0; nt < 4; ++nt){
        short8 bb = *(const short8*)&sK[nt*16 + cl][kk*32 + rowg*8];
        c[b][nt] = MFMA16(a, bb, c[b][nt]);
      }
    }
  }
  int lenv[8];
#pragma unroll
  for (int b = 0; b < 8; ++b) lenv[b] = lens[b];
  const int q0 = qt*64 + w*16 + rowg*4;
  float cs[8][4];
#pragma unroll
  for (int b = 0; b < 8; ++b)
#pragma unroll
    for (int nt = 0; nt < 4; ++nt) cs[b][nt] = 0.f;
#pragma unroll
  for (int nt = 0; nt < 4; ++nt){
#pragma unroll
    for (int r = 0; r < 4; ++r){
      float m = c[0][nt][r];
#pragma unroll
      for (int b = 1; b < 8; ++b) m = fmaxf(m, c[b][nt][r]);
      float e[8], s = 0.f;
#pragma unroll
      for (int b = 0; b < 8; ++b){ e[b] = __builtin_amdgcn_exp2f((c[b][nt][r] - m)*RSCALE_LG); s += e[b]; }
      float ri = __builtin_amdgcn_rcpf(s);
#pragma unroll
      for (int b = 0; b < 8; ++b)
        if (q0 + r < lenv[b]) cs[b][nt] += e[b]*ri;
    }
  }
#pragma unroll
  for (int b = 0; b < 8; ++b)
#pragma unroll
    for (int nt = 0; nt < 4; ++nt){
      float v = cs[b][nt];
      v += __shfl_xor(v, 16); v += __shfl_xor(v, 32);
      if (l < 16) atomicAdd(&cbuf[b][nt*16 + l], v);
    }
  __syncthreads();
  for (int i = tid; i < 512; i += 256)
    atomicAdd(&colsum[(size_t)(i >> 6)*2048 + kt*64 + (i & 63)], cbuf[i >> 6][i & 63]);
}

// ---------------- xg = in @ Wih^T, scaled/biased for exp2-based gates ----------------
template<int KIN>
__global__ __launch_bounds__(256, 1) void k_xg(const int* lens, char* ws){
  const int tt = blockIdx.x, b = blockIdx.y, dir = blockIdx.z;
  constexpr int LAYER = (KIN == 128) ? 0 : 1;
  const u16* in = (KIN == 128) ? (const u16*)(ws + OFS_PAD) : (const u16*)(ws + OFS_H1);
  const u16* wmat = ((KIN == 128) ? (const u16*)(ws + OFS_WIH0) : (const u16*)(ws + OFS_WIH1))
                    + (size_t)dir*384*KIN;
  const float* biasx = (const float*)(ws + OFS_BIASX) + (LAYER*2 + dir)*384;
  float* xg = (float*)(ws + OFS_XG) + (size_t)dir*2048*3072;
  const int lenb = lens[b];
  __shared__ __align__(16) u16 sA[64][KIN + 8];
  constexpr int CH = KIN/8;
  const int tid = threadIdx.x, w = tid >> 6, l = tid & 63, rowg = l >> 4, cl = l & 15;
  for (int idx = tid; idx < 64*CH; idx += 256){
    int row = idx / CH, chn = idx % CH;
    int t = tt*64 + row;
    int tr = dir ? ((t < lenb) ? (lenb - 1 - t) : t) : t;
    *(u16x8*)&sA[row][chn*8] = *(const u16x8*)(in + ((size_t)(b*2048 + tr))*KIN + chn*8);
  }
  __syncthreads();
  f32x4 acc[24];
#pragma unroll
  for (int nt = 0; nt < 24; ++nt) acc[nt] = f32x4{0.f,0.f,0.f,0.f};
#pragma unroll
  for (int kk = 0; kk < KIN/32; ++kk){
    short8 a = *(const short8*)&sA[w*16 + cl][kk*32 + rowg*8];
#pragma unroll
    for (int nt = 0; nt < 24; ++nt){
      short8 bb = *(const short8*)(wmat + (size_t)(nt*16 + cl)*KIN + kk*32 + rowg*8);
      acc[nt] = MFMA16(a, bb, acc[nt]);
    }
  }
#pragma unroll
  for (int nt = 0; nt < 24; ++nt){
    const int g = nt*16 + cl;
    const float bx = biasx[g];
    const float sc = (nt < 16) ? -LOG2E_C : TWOLOG2E_C;
#pragma unroll
    for (int r = 0; r < 4; ++r){
      const int t = tt*64 + w*16 + rowg*4 + r;
      xg[((size_t)t*8 + b)*384 + g] = sc*acc[nt][r] + bx;
    }
  }
}

// ---------------- GRU recurrence ----------------
DEVINL void loadset(const float* px, const int (&oR)[2][4], const int (&oN)[4],
                    float (&XR)[2][4], float (&XZ)[2][4], float (&XN)[4]){
#pragma unroll
  for (int p = 0; p < 2; ++p)
#pragma unroll
    for (int r = 0; r < 4; ++r){ XR[p][r] = px[oR[p][r]]; XZ[p][r] = px[oR[p][r] + 128]; }
#pragma unroll
  for (int r = 0; r < 4; ++r) XN[r] = px[oN[r]];
}

DEVINL void rec_step(int T, int NEXT_T, int dir, int lenb, int rowg, int cl, int b8, int pe, int j0,
    int cur, u16 (&hb)[2][2048],
    const short8 (&aR)[2][4], const short8 (&aZ)[2][4], const short8 (&aN)[2][4],
    const float (&bnU)[2][4], float (&hprev)[4],
    float (&XR)[2][4], float (&XZ)[2][4], float (&XN)[4],
    const float* xg, const int (&oR)[2][4], const int (&oN)[4], u16* outp)
{
  (void)cl;
  short8 bf[4];
#pragma unroll
  for (int kk = 0; kk < 4; ++kk)
    bf[kk] = *(const short8*)(&hb[cur][0] + (size_t)(kk*4 + rowg)*128 + (cl)*8);
  f32x4 cR[2], cZ[2], cN[2];
#pragma unroll
  for (int p = 0; p < 2; ++p){
    cR[p] = f32x4{XR[p][0], XR[p][1], XR[p][2], XR[p][3]};
    cZ[p] = f32x4{XZ[p][0], XZ[p][1], XZ[p][2], XZ[p][3]};
    cN[p] = f32x4{bnU[p][0], bnU[p][1], bnU[p][2], bnU[p][3]};
  }
#pragma unroll
  for (int kk = 0; kk < 4; ++kk){
#pragma unroll
    for (int p = 0; p < 2; ++p){
      cR[p] = MFMA16(aR[p][kk], bf[kk], cR[p]);
      cZ[p] = MFMA16(aZ[p][kk], bf[kk], cZ[p]);
      cN[p] = MFMA16(aN[p][kk], bf[kk], cN[p]);
    }
  }
  float hnv[4], ov[4];
  const bool valid = T < lenb;
#pragma unroll
  for (int r = 0; r < 4; ++r){
    float gR = selpack(cR[0][r], cR[1][r], pe);
    float gZ = selpack(cZ[0][r], cZ[1][r], pe);
    float gN = selpack(cN[0][r], cN[1][r], pe);
    float Rg = __builtin_amdgcn_rcpf(1.f + __builtin_amdgcn_exp2f(gR));  // sigmoid(pre_r)
    float Zg = __builtin_amdgcn_rcpf(1.f + __builtin_amdgcn_exp2f(gZ));  // sigmoid(pre_z)
    float y  = XN[r] + Rg*gN;                                            // 2log2e * n_pre
    float NN = 1.f - 2.f*__builtin_amdgcn_rcpf(1.f + __builtin_amdgcn_exp2f(y)); // tanh(n_pre)
    float hn = NN + Zg*(hprev[r] - NN);
    float hv = valid ? hn : hprev[r];
    hprev[r] = hv; hnv[r] = hv;
    ov[r] = valid ? hn : 0.f;
  }
  // prefetch xg for NEXT_T (distance 2)
  loadset(xg + (size_t)NEXT_T*3072, oR, oN, XR, XZ, XN);
  u32 hw0 = (u32)f2bf(hnv[0]) | ((u32)f2bf(hnv[1]) << 16);
  u32 hw1 = (u32)f2bf(hnv[2]) | ((u32)f2bf(hnv[3]) << 16);
  u32 ow0 = (u32)f2bf(ov[0]) | ((u32)f2bf(ov[1]) << 16);
  u32 ow1 = (u32)f2bf(ov[2]) | ((u32)f2bf(ov[3]) << 16);
  *reinterpret_cast<u32x2*>(&hb[cur^1][0] + (size_t)((j0 >> 3)*16 + b8)*8 + (j0 & 7)) = u32x2{hw0, hw1};
  const int t_o = (dir == 0) ? T : (valid ? (lenb - 1 - T) : T);
  *reinterpret_cast<u32x2*>(outp + (size_t)t_o*256) = u32x2{ow0, ow1};
  asm volatile("s_waitcnt lgkmcnt(0)" ::: "memory");
  __builtin_amdgcn_s_barrier();
  asm volatile("" ::: "memory");
}

__global__ __launch_bounds__(256, 1) void k_rec(const float* xg_all, const float* whh_all,
    const float* bhhn_all, const int* lens, u16* out)
{
  const int dir = blockIdx.x;
  const float* xg  = xg_all + (size_t)dir*2048*3072;
  const float* whh = whh_all + (size_t)dir*384*128;
  const float* bnd = bhhn_all + dir*128;
  const int tid = threadIdx.x;
  const int w = tid >> 6, l = tid & 63;
  const int rowg = l >> 4, cl = l & 15, b8 = l & 7, pe = (l >> 3) & 1;
  __shared__ __align__(16) u16 hb[2][2048];
  for (int i = tid; i < 4096; i += 256) (&hb[0][0])[i] = 0;
  short8 aR[2][4], aZ[2][4], aN[2][4];
#pragma unroll
  for (int p = 0; p < 2; ++p){
#pragma unroll
    for (int kk = 0; kk < 4; ++kk){
      int k0 = kk*32 + rowg*8;
      aR[p][kk] = ld8cvt(whh + (size_t)((2*w + p)*16 + cl)*128 + k0, -LOG2E_C);
      aZ[p][kk] = ld8cvt(whh + (size_t)((8 + 2*w + p)*16 + cl)*128 + k0, -LOG2E_C);
      aN[p][kk] = ld8cvt(whh + (size_t)((16 + 2*w + p)*16 + cl)*128 + k0, TWOLOG2E_C);
    }
  }
  float bnU[2][4];
#pragma unroll
  for (int p = 0; p < 2; ++p)
#pragma unroll
    for (int r = 0; r < 4; ++r) bnU[p][r] = bnd[(2*w + p)*16 + rowg*4 + r];
  const int lenb = lens[b8];
  const int j0 = (2*w + pe)*16 + rowg*4;
  int oR[2][4], oN[4];
#pragma unroll
  for (int p = 0; p < 2; ++p)
#pragma unroll
    for (int r = 0; r < 4; ++r) oR[p][r] = b8*384 + (2*w + p)*16 + rowg*4 + r;
#pragma unroll
  for (int r = 0; r < 4; ++r) oN[r] = b8*384 + 256 + j0 + r;
  u16* outp = out + (size_t)b8*2048*256 + dir*128 + j0;
  float hprev[4] = {0.f, 0.f, 0.f, 0.f};
  float xR0[2][4], xZ0[2][4], xN0[4], xR1[2][4], xZ1[2][4], xN1[4];
  __syncthreads();
  loadset(xg + (size_t)0*3072, oR, oN, xR0, xZ0, xN0);
  loadset(xg + (size_t)1*3072, oR, oN, xR1, xZ1, xN1);
  int cur = 0;
  for (int t = 0; t < 2048; t += 2){
    rec_step(t,   (t + 2 < 2048) ? (t + 2) : 2047, dir, lenb, rowg, cl, b8, pe, j0, cur, hb,
             aR, aZ, aN, bnU, hprev, xR0, xZ0, xN0, xg, oR, oN, outp);
    cur ^= 1;
    rec_step(t+1, (t + 3 < 2048) ? (t + 3) : 2047, dir, lenb, rowg, cl, b8, pe, j0, cur, hb,
             aR, aZ, aN, bnU, hprev, xR1, xZ1, xN1, xg, oR, oN, outp);
    cur ^= 1;
  }
}

// ---------------- encW = enc @ Wa2^T ----------------
__global__ __launch_bounds__(256, 1) void k_encw(char* ws){
  const int tt = blockIdx.x, b = blockIdx.y;
  const u16* in = (const u16*)(ws + OFS_ENC);
  const u16* wmat = (const u16*)(ws + OFS_WA2);
  float* out = (float*)(ws + OFS_ENCW);
  __shared__ __align__(16) u16 sA[64][264];
  const int tid = threadIdx.x, w = tid >> 6, l = tid & 63, rowg = l >> 4, cl = l & 15;
  for (int idx = tid; idx < 64*32; idx += 256){
    int row = idx >> 5, chn = idx & 31;
    int t = tt*64 + row;
    *(u16x8*)&sA[row][chn*8] = *(const u16x8*)(in + ((size_t)(b*2048 + t))*256 + chn*8);
  }
  __syncthreads();
  f32x4 acc[16];
#pragma unroll
  for (int nt = 0; nt < 16; ++nt) acc[nt] = f32x4{0.f,0.f,0.f,0.f};
#pragma unroll
  for (int kk = 0; kk < 8; ++kk){
    short8 a = *(const short8*)&sA[w*16 + cl][kk*32 + rowg*8];
#pragma unroll
    for (int nt = 0; nt < 16; ++nt){
      short8 bb = *(const short8*)(wmat + (size_t)(nt*16 + cl)*256 + kk*32 + rowg*8);
      acc[nt] = MFMA16(a, bb, acc[nt]);
    }
  }
#pragma unroll
  for (int nt = 0; nt < 16; ++nt){
    int h = nt*16 + cl;
#pragma unroll
    for (int r = 0; r < 4; ++r){
      int t = tt*64 + w*16 + rowg*4 + r;
      out[((size_t)(b*2048 + t))*256 + h] = acc[nt][r];
    }
  }
}

// ---------------- sa[b][d] = sum_k colsum[b][k] * V[b][k][d] ----------------
__global__ __launch_bounds__(256) void k_sa(char* ws){
  const int b = blockIdx.x, d = threadIdx.x;
  const float* cs = (const float*)(ws + OFS_CS) + (size_t)b*2048;
  const u16* V = (const u16*)(ws + OFS_V) + (size_t)b*2048*256;
  float a0 = 0.f, a1 = 0.f, a2 = 0.f, a3 = 0.f;
  for (int k = 0; k < 2048; k += 4){
    a0 += cs[k + 0]*bf2f(V[(size_t)(k + 0)*256 + d]);
    a1 += cs[k + 1]*bf2f(V[(size_t)(k + 1)*256 + d]);
    a2 += cs[k + 2]*bf2f(V[(size_t)(k + 2)*256 + d]);
    a3 += cs[k + 3]*bf2f(V[(size_t)(k + 3)*256 + d]);
  }
  ((float*)(ws + OFS_SA))[b*256 + d] = (a0 + a1) + (a2 + a3);
}

// ---------------- additive-attn scores (pre-softmax, masked) ----------------
__global__ __launch_bounds__(256) void k_res(const int* lens, const float* WaW, const float* Wab,
    const float* VTw, const float* VTb, char* ws){
  const int b = blockIdx.x, x = blockIdx.y, chb = blockIdx.z;
  const float* tm = (const float*)(ws + OFS_TM) + b*128;
  const float* sa = (const float*)(ws + OFS_SA) + b*256;
  const float* encW = (const float*)(ws + OFS_ENCW);
  float* res = (float*)(ws + OFS_RES) + ((size_t)b*2 + x)*2048;
  __shared__ float sw[256];
  __shared__ float vt[256];
  const int tid = threadIdx.x;
  {
    int h = tid;
    float acc = Wab[h];
    if (x == 0){
      for (int j = 0; j < 128; ++j)
        acc += tm[j]*(1.f/2048.f)*(WaW[(size_t)h*512 + 2*j] + WaW[(size_t)h*512 + 2*j + 1]);
    } else {
      for (int k = 0; k < 256; ++k) acc += sa[k]*WaW[(size_t)h*512 + k];
    }
    sw[h] = acc;
    vt[h] = VTw[h];
  }
  __syncthreads();
  const int lenb = lens[b];
  const int lsub = tid >> 2, q = tid & 3;
  const float vtb = VTb[0];
#pragma unroll
  for (int pass = 0; pass < 4; ++pass){
    const int ll = chb*256 + pass*64 + lsub;
    const float* er = encW + ((size_t)(b*2048 + ll))*256 + q*64;
    float racc = 0.f;
    for (int j = 0; j < 64; ++j){
      float u = er[j] + sw[q*64 + j];
      float th = 1.f - 2.f*__builtin_amdgcn_rcpf(1.f + __builtin_amdgcn_exp2f(u*TWOLOG2E_C));
      racc += th*vt[q*64 + j];
    }
    racc += __shfl_xor(racc, 1);
    racc += __shfl_xor(racc, 2);
    if (q == 0) res[ll] = (ll < lenb) ? (racc + vtb) : 0.f;
  }
}

// ---------------- softmax over L + weighted enc sum → d1/d2 ----------------
__global__ __launch_bounds__(256) void k_attnfin(char* ws){
  const int b = blockIdx.x, x = blockIdx.y;
  const float* res = (const float*)(ws + OFS_RES) + ((size_t)b*2 + x)*2048;
  const u16* enc = (const u16*)(ws + OFS_ENC);
  float* dvec = (float*)(ws + OFS_DV);
  __shared__ float sv[2048];
  __shared__ float red[8];
  const int tid = threadIdx.x;
  float m = -3.0e38f;
  for (int i = tid; i < 2048; i += 256){ float v = res[i]; sv[i] = v; m = fmaxf(m, v); }
#pragma unroll
  for (int o = 1; o < 64; o <<= 1) m = fmaxf(m, __shfl_xor(m, o));
  if ((tid & 63) == 0) red[tid >> 6] = m;
  __syncthreads();
  m = fmaxf(fmaxf(red[0], red[1]), fmaxf(red[2], red[3]));
  __syncthreads();
  float s = 0.f;
  for (int i = tid; i < 2048; i += 256){ float e = __builtin_amdgcn_exp2f((sv[i] - m)*LOG2E_C); sv[i] = e; s += e; }
#pragma unroll
  for (int o = 1; o < 64; o <<= 1) s += __shfl_xor(s, o);
  if ((tid & 63) == 0) red[tid >> 6] = s;
  __syncthreads();
  const float S = red[0] + red[1] + red[2] + red[3];
  const float ri = 1.0f/S;
  const int h = tid;
  float a0 = 0.f, a1 = 0.f, a2 = 0.f, a3 = 0.f;
  for (int l0 = 0; l0 < 2048; l0 += 4){
    a0 += sv[l0 + 0]*bf2f(enc[((size_t)(b*2048 + l0 + 0))*256 + h]);
    a1 += sv[l0 + 1]*bf2f(enc[((size_t)(b*2048 + l0 + 1))*256 + h]);
    a2 += sv[l0 + 2]*bf2f(enc[((size_t)(b*2048 + l0 + 2))*256 + h]);
    a3 += sv[l0 + 3]*bf2f(enc[((size_t)(b*2048 + l0 + 3))*256 + h]);
  }
  dvec[((size_t)b*2 + x)*256 + h] = ((a0 + a1) + (a2 + a3))*ri;
}

// ---------------- final FC ----------------
__global__ __launch_bounds__(64) void k_final(const float* fcw, const float* fcb, char* ws, float* outp){
  const int i = threadIdx.x;
  if (i >= 48) return;
  const int b = i/6, o = i%6;
  const float* dv = (const float*)(ws + OFS_DV);
  float acc = fcb[o];
  for (int h = 0; h < 256; ++h)
    acc += 0.5f*(dv[((size_t)b*2 + 0)*256 + h] + dv[((size_t)b*2 + 1)*256 + h])*fcw[o*256 + h];
  outp[i] = acc;
}

// ---------------- host ----------------
extern "C" void kernel_launch(void* const* d_in, const int* in_sizes, int n_in,
                              void* d_out, int out_size, void* d_ws, size_t ws_size,
                              hipStream_t stream)
{
  const int* tok    = (const int*)d_in[0];
  const int* lens   = (const int*)d_in[1];
  const float* embed= (const float*)d_in[2];
  const float* wih0 = (const float*)d_in[3];
  const float* whh0 = (const float*)d_in[4];
  const float* bih0 = (const float*)d_in[5];
  const float* bhh0 = (const float*)d_in[6];
  const float* wih1 = (const float*)d_in[7];
  const float* whh1 = (const float*)d_in[8];
  const float* bih1 = (const float*)d_in[9];
  const float* bhh1 = (const float*)d_in[10];
  const float* convw= (const float*)d_in[11];
  const float* convb= (const float*)d_in[12];
  const float* WaW  = (const float*)d_in[13];
  const float* Wab  = (const float*)d_in[14];
  const float* VTw  = (const float*)d_in[15];
  const float* VTb  = (const float*)d_in[16];
  const float* Qw   = (const float*)d_in[17];
  const float* Kw   = (const float*)d_in[18];
  const float* Vw   = (const float*)d_in[19];
  const float* fcw  = (const float*)d_in[20];
  const float* fcb  = (const float*)d_in[21];
  char* ws = (char*)d_ws;
  float* outp = (float*)d_out;

  hipLaunchKernelGGL(k_prep, dim3(2048), dim3(256), 0, stream,
      tok, lens, embed, wih0, wih1, bih0, bhh0, bih1, bhh1, convw, WaW, Qw, Kw, Vw, ws);
  hipLaunchKernelGGL((k_conv<2051,2050,0>), dim3(33,8), dim3(256), 0, stream, lens, convb, ws);
  hipLaunchKernelGGL((k_conv<2050,2049,1>), dim3(33,8), dim3(256), 0, stream, lens, convb, ws);
  hipLaunchKernelGGL((k_conv<2049,2048,2>), dim3(32,8), dim3(256), 0, stream, lens, convb, ws);
  hipLaunchKernelGGL(k_qkv, dim3(32,8,3), dim3(256), 0, stream, ws);
  hipLaunchKernelGGL(k_scores, dim3(32,32), dim3(256), 0, stream, lens, ws);
  hipLaunchKernelGGL((k_xg<128>), dim3(32,8,2), dim3(256), 0, stream, lens, ws);
  hipLaunchKernelGGL(k_rec, dim3(2), dim3(256), 0, stream,
      (const float*)(ws + OFS_XG), whh0, (const float*)(ws + OFS_BHHN), lens, (u16*)(ws + OFS_H1));
  hipLaunchKernelGGL((k_xg<256>), dim3(32,8,2), dim3(256), 0, stream, lens, ws);
  hipLaunchKernelGGL(k_rec, dim3(2), dim3(256), 0, stream,
      (const float*)(ws + OFS_XG), whh1, (const float*)(ws + OFS_BHHN) + 2*128, lens, (u16*)(ws + OFS_ENC));
  hipLaunchKernelGGL(k_encw, dim3(32,8), dim3(256), 0, stream, ws);
  hipLaunchKernelGGL(k_sa, dim3(8), dim3(256), 0, stream, ws);
  hipLaunchKernelGGL(k_res, dim3(8,2,8), dim3(256), 0, stream, lens, WaW, Wab, VTw, VTb, ws);
  hipLaunchKernelGGL(k_attnfin, dim3(8,2), dim3(256), 0, stream, ws);
  hipLaunchKernelGGL(k_final, dim3(1), dim3(64), 0, stream, fcw, fcb, ws, outp);
  (void)in_sizes; (void)n_in; (void)out_size; (void)ws_size;
}

// Round 2
// 2905.722 us; speedup vs baseline: 1.9533x; 1.9533x over previous
//
#include <hip/hip_runtime.h>
#include <stdint.h>

typedef unsigned short u16;
typedef unsigned int u32;
typedef __attribute__((ext_vector_type(8))) short short8;
typedef __attribute__((ext_vector_type(8))) u16 u16x8;
typedef __attribute__((ext_vector_type(4))) float f32x4;
typedef __attribute__((ext_vector_type(2))) u32 u32x2;

#define DEVINL static __device__ __forceinline__

#if !__has_builtin(__builtin_amdgcn_exp2f)
#define __builtin_amdgcn_exp2f(x) exp2f(x)
#endif
#if !__has_builtin(__builtin_amdgcn_rcpf)
#define __builtin_amdgcn_rcpf(x) (1.0f/(x))
#endif

#define MFMA16(a, b, c) __builtin_amdgcn_mfma_f32_16x16x32_bf16((a), (b), (c), 0, 0, 0)

constexpr float LOG2E_C    = 1.4426950408889634f;
constexpr float TWOLOG2E_C = 2.8853900817779268f;
constexpr float RSCALE_LG  = 1.4426950408889634f / 11.313708498984761f; // log2e / sqrt(128)

// ---------------- workspace layout (bytes) ----------------
constexpr size_t A256(size_t x){ return (x + 255) & ~(size_t)255; }
constexpr size_t OFS_EMB   = 0;                                         // u16 [8][2051][128] unmasked emb
constexpr size_t OFS_PAD   = A256(OFS_EMB  + (size_t)8*2051*128*2);     // u16 [8][2048][128] masked
constexpr size_t OFS_X1    = A256(OFS_PAD  + (size_t)8*2048*128*2);     // u16 [8][2050][128]
constexpr size_t OFS_X2    = A256(OFS_X1   + (size_t)8*2050*128*2);     // u16 [8][2049][128]
constexpr size_t OFS_QKVW  = A256(OFS_X2   + (size_t)8*2049*128*2);     // u16 [3][256][128] folded
constexpr size_t OFS_WA2   = A256(OFS_QKVW + (size_t)3*256*128*2);      // u16 [256][256]
constexpr size_t OFS_CONVW = A256(OFS_WA2  + (size_t)256*256*2);        // u16 [3][128][256]
constexpr size_t OFS_WIH0  = A256(OFS_CONVW+ (size_t)3*128*256*2);      // u16 [2][384][128]
constexpr size_t OFS_WIH1  = A256(OFS_WIH0 + (size_t)2*384*128*2);      // u16 [2][384][256]
constexpr size_t OFS_BIASX = A256(OFS_WIH1 + (size_t)2*384*256*2);      // f32 [2][2][384] scaled biases
constexpr size_t OFS_BHHN  = A256(OFS_BIASX+ (size_t)2*2*384*4);        // f32 [2][2][128] 2log2e*bhh_n
constexpr size_t OFS_Q     = A256(OFS_BHHN + (size_t)2*2*128*4);        // u16 [8][2048][256]
constexpr size_t OFS_K     = A256(OFS_Q    + (size_t)8*2048*256*2);
constexpr size_t OFS_V     = A256(OFS_K    + (size_t)8*2048*256*2);
constexpr size_t OFS_CS    = A256(OFS_V    + (size_t)8*2048*256*2);     // f32 [8][2048] colsum
constexpr size_t OFS_TM    = A256(OFS_CS   + (size_t)8*2048*4);         // f32 [8][128] tmean sums
constexpr size_t OFS_XG    = A256(OFS_TM   + (size_t)8*128*4);          // f32 [2][2048][8][384]
constexpr size_t OFS_H1    = A256(OFS_XG   + (size_t)2*2048*8*384*4);   // u16 [8][2048][256]
constexpr size_t OFS_ENC   = A256(OFS_H1   + (size_t)8*2048*256*2);     // u16 [8][2048][256]
constexpr size_t OFS_ENCW  = A256(OFS_ENC  + (size_t)8*2048*256*2);     // f32 [8][2048][256]
constexpr size_t OFS_SA    = A256(OFS_ENCW + (size_t)8*2048*256*4);     // f32 [8][256]
constexpr size_t OFS_RES   = A256(OFS_SA   + (size_t)8*256*4);          // f32 [8][2][2048]
constexpr size_t OFS_DV    = A256(OFS_RES  + (size_t)8*2*2048*4);       // f32 [8][2][256]

// ---------------- helpers ----------------
DEVINL u16 f2bf(float f){
  u32 u = __builtin_bit_cast(u32, f);
  u32 r = (u + 0x7FFFu + ((u >> 16) & 1u)) >> 16;
  return (u16)r;
}
DEVINL float bf2f(u16 s){ return __builtin_bit_cast(float, (u32)s << 16); }

DEVINL short8 ld8cvt(const float* p, float sc){
  short8 o;
#pragma unroll
  for (int e = 0; e < 8; ++e) o[e] = (short)f2bf(p[e]*sc);
  return o;
}

DEVINL u32 cvtpk(float lo, float hi){
  u32 r;
  asm("v_cvt_pk_bf16_f32 %0, %1, %2" : "=v"(r) : "v"(lo), "v"(hi));
  return r;
}

// ---------------- prep: gathers, weight conversions, zeroing ----------------
__global__ __launch_bounds__(256) void k_prep(
    const int* tok, const int* lens, const float* embed,
    const float* wih0, const float* wih1,
    const float* bih0, const float* bhh0, const float* bih1, const float* bhh1,
    const float* convw, const float* WaW, const float* Qw, const float* Kw, const float* Vw,
    char* ws)
{
  u16* emb_bf   = (u16*)(ws + OFS_EMB);
  u16* pad_bf   = (u16*)(ws + OFS_PAD);
  u16* qkvw     = (u16*)(ws + OFS_QKVW);
  u16* wa2      = (u16*)(ws + OFS_WA2);
  u16* convw_bf = (u16*)(ws + OFS_CONVW);
  u16* wih0_bf  = (u16*)(ws + OFS_WIH0);
  u16* wih1_bf  = (u16*)(ws + OFS_WIH1);
  float* biasx  = (float*)(ws + OFS_BIASX);
  float* bhhn   = (float*)(ws + OFS_BHHN);
  float* colsum = (float*)(ws + OFS_CS);
  float* tmean  = (float*)(ws + OFS_TM);
  const int S0 = 8*2051*128, S1 = 8*2048*128, S2 = 3*256*128, S3 = 256*256, S4 = 3*128*256;
  const int S5 = 2*384*128, S6 = 2*384*256, S7 = 2*2*384 + 2*2*128, S8 = 8*2048 + 8*128;
  const int TOT = S0+S1+S2+S3+S4+S5+S6+S7+S8;
  for (int i = blockIdx.x*256 + threadIdx.x; i < TOT; i += gridDim.x*256){
    int j = i;
    if (j < S0){
      int b = j / (2051*128); int r = j - b*(2051*128); int t = r >> 7, dd = r & 127;
      emb_bf[j] = f2bf(embed[(size_t)tok[b*4000 + t]*128 + dd]);
      continue;
    }
    j -= S0;
    if (j < S1){
      int b = j >> 18; int r = j & 262143; int t = r >> 7, dd = r & 127;
      float v = (t < lens[b]) ? embed[(size_t)tok[b*4000 + t]*128 + dd] : 0.f;
      pad_bf[j] = f2bf(v); continue;
    }
    j -= S1;
    if (j < S2){
      int z = j >> 15; int r = j & 32767; int o = r >> 7, k2 = r & 127;
      const float* W = (z == 0) ? Qw : (z == 1) ? Kw : Vw;
      qkvw[j] = f2bf(W[o*256 + k2] + W[o*256 + 128 + k2]); continue;
    }
    j -= S2;
    if (j < S3){ int h = j >> 8, k2 = j & 255; wa2[j] = f2bf(WaW[(size_t)h*512 + 256 + k2]); continue; }
    j -= S3;
    if (j < S4){
      int ly = j >> 15; int r = j & 32767; int o = r >> 8, k2 = r & 255;
      int i2 = k2 & 127, kap = k2 >> 7;
      convw_bf[j] = f2bf(convw[((size_t)(ly*128 + o)*128 + i2)*2 + kap]); continue;
    }
    j -= S4;
    if (j < S5){ wih0_bf[j] = f2bf(wih0[j]); continue; }
    j -= S5;
    if (j < S6){ wih1_bf[j] = f2bf(wih1[j]); continue; }
    j -= S6;
    if (j < S7){
      if (j < 1536){
        int ly = j / 768; int r = j - ly*768; int d = r / 384, g = r % 384;
        float bi = (ly ? bih1 : bih0)[d*384 + g];
        float bh = (ly ? bhh1 : bhh0)[d*384 + g];
        biasx[j] = (g < 256) ? (-LOG2E_C*(bi + bh)) : (TWOLOG2E_C*bi);
      } else {
        int j2 = j - 1536; int ly = j2 >> 8; int r = j2 & 255; int d = r >> 7, jj = r & 127;
        bhhn[j2] = TWOLOG2E_C*((ly ? bhh1 : bhh0)[d*384 + 256 + jj]);
      }
      continue;
    }
    j -= S7;
    if (j < 8*2048) colsum[j] = 0.f; else tmean[j - 8*2048] = 0.f;
  }
}

// ---------------- conv1d (k=2, VALID) as im2col MFMA; layer 2 accumulates tmean ----------------
template<int LIN, int LOUT, int LAYER>
__global__ __launch_bounds__(256, 1) void k_conv(const int* lens, const float* convb, char* ws){
  const int tt = blockIdx.x, b = blockIdx.y;
  const u16* in = (LAYER == 0) ? (const u16*)(ws + OFS_EMB)
                : (LAYER == 1) ? (const u16*)(ws + OFS_X1) : (const u16*)(ws + OFS_X2);
  u16* out = (LAYER == 0) ? (u16*)(ws + OFS_X1) : (u16*)(ws + OFS_X2);
  const u16* wmat = (const u16*)(ws + OFS_CONVW) + (size_t)LAYER*128*256;
  float* tmean = (float*)(ws + OFS_TM);
  __shared__ __align__(16) u16 sA[65][136];
  const int tid = threadIdx.x, w = tid >> 6, l = tid & 63, rowg = l >> 4, cl = l & 15;
  for (int idx = tid; idx < 65*16; idx += 256){
    int row = idx >> 4, chn = idx & 15;
    int t = tt*64 + row;
    u16x8 v = {0,0,0,0,0,0,0,0};
    if (t < LIN) v = *(const u16x8*)(in + ((size_t)(b*LIN + t))*128 + chn*8);
    *(u16x8*)&sA[row][chn*8] = v;
  }
  __syncthreads();
  f32x4 acc[8];
#pragma unroll
  for (int nt = 0; nt < 8; ++nt) acc[nt] = f32x4{0.f,0.f,0.f,0.f};
#pragma unroll
  for (int kk = 0; kk < 8; ++kk){
    const int rofs = (kk >= 4) ? 1 : 0;
    short8 a = *(const short8*)&sA[w*16 + cl + rofs][(kk & 3)*32 + rowg*8];
#pragma unroll
    for (int nt = 0; nt < 8; ++nt){
      short8 bb = *(const short8*)(wmat + (size_t)(nt*16 + cl)*256 + kk*32 + rowg*8);
      acc[nt] = MFMA16(a, bb, acc[nt]);
    }
  }
  if (LAYER < 2){
#pragma unroll
    for (int nt = 0; nt < 8; ++nt){
      int o = nt*16 + cl;
      float bias = convb[LAYER*128 + o];
#pragma unroll
      for (int r = 0; r < 4; ++r){
        int t = tt*64 + w*16 + rowg*4 + r;
        if (t < LOUT) out[((size_t)(b*LOUT + t))*128 + o] = f2bf(fmaxf(acc[nt][r] + bias, 0.f));
      }
    }
  } else {
    const int lenb = lens[b];
#pragma unroll
    for (int nt = 0; nt < 8; ++nt){
      int o = nt*16 + cl;
      float bias = convb[2*128 + o];
      float s = 0.f;
#pragma unroll
      for (int r = 0; r < 4; ++r){
        int t = tt*64 + w*16 + rowg*4 + r;
        if (t < lenb) s += fmaxf(acc[nt][r] + bias, 0.f);
      }
      s += __shfl_xor(s, 16); s += __shfl_xor(s, 32);
      if (l < 16) atomicAdd(&tmean[b*128 + o], s);
    }
  }
}

// ---------------- Q/K/V = pad_bf @ folded-weight^T ----------------
__global__ __launch_bounds__(256, 1) void k_qkv(char* ws){
  const int tt = blockIdx.x, b = blockIdx.y, z = blockIdx.z;
  const u16* in = (const u16*)(ws + OFS_PAD);
  const u16* wmat = (const u16*)(ws + OFS_QKVW) + (size_t)z*256*128;
  u16* out = (u16*)(ws + ((z == 0) ? OFS_Q : (z == 1) ? OFS_K : OFS_V));
  __shared__ __align__(16) u16 sA[64][136];
  const int tid = threadIdx.x, w = tid >> 6, l = tid & 63, rowg = l >> 4, cl = l & 15;
  for (int idx = tid; idx < 64*16; idx += 256){
    int row = idx >> 4, chn = idx & 15;
    int t = tt*64 + row;
    *(u16x8*)&sA[row][chn*8] = *(const u16x8*)(in + ((size_t)(b*2048 + t))*128 + chn*8);
  }
  __syncthreads();
  f32x4 acc[16];
#pragma unroll
  for (int nt = 0; nt < 16; ++nt) acc[nt] = f32x4{0.f,0.f,0.f,0.f};
#pragma unroll
  for (int kk = 0; kk < 4; ++kk){
    short8 a = *(const short8*)&sA[w*16 + cl][kk*32 + rowg*8];
#pragma unroll
    for (int nt = 0; nt < 16; ++nt){
      short8 bb = *(const short8*)(wmat + (size_t)(nt*16 + cl)*128 + kk*32 + rowg*8);
      acc[nt] = MFMA16(a, bb, acc[nt]);
    }
  }
#pragma unroll
  for (int nt = 0; nt < 16; ++nt){
    int o = nt*16 + cl;
#pragma unroll
    for (int r = 0; r < 4; ++r){
      int t = tt*64 + w*16 + rowg*4 + r;
      out[((size_t)(b*2048 + t))*256 + o] = f2bf(acc[nt][r]);
    }
  }
}

// ---------------- scores: softmax over batch axis, accumulate colsum[b][k] ----------------
__global__ __launch_bounds__(256, 1) void k_scores(const int* lens, char* ws){
  const int kt = blockIdx.x, qt = blockIdx.y;
  const u16* Qp = (const u16*)(ws + OFS_Q);
  const u16* Kp = (const u16*)(ws + OFS_K);
  float* colsum = (float*)(ws + OFS_CS);
  __shared__ __align__(16) u16 sQ[64][264];
  __shared__ __align__(16) u16 sK[64][264];
  __shared__ float cbuf[8][64];
  const int tid = threadIdx.x, w = tid >> 6, l = tid & 63, rowg = l >> 4, cl = l & 15;
  for (int i = tid; i < 512; i += 256) cbuf[i >> 6][i & 63] = 0.f;
  f32x4 c[8][4];
#pragma unroll
  for (int b = 0; b < 8; ++b)
#pragma unroll
    for (int nt = 0; nt < 4; ++nt) c[b][nt] = f32x4{0.f,0.f,0.f,0.f};
#pragma unroll
  for (int b = 0; b < 8; ++b){
    __syncthreads();
    for (int idx = tid; idx < 4096; idx += 256){
      int which = idx >> 11, row = (idx >> 5) & 63, ch = idx & 31;
      if (which){
        *(u16x8*)&sK[row][ch*8] = *(const u16x8*)(Kp + ((size_t)(b*2048 + kt*64 + row))*256 + ch*8);
      } else {
        *(u16x8*)&sQ[row][ch*8] = *(const u16x8*)(Qp + ((size_t)(b*2048 + qt*64 + row))*256 + ch*8);
      }
    }
    __syncthreads();
#pragma unroll
    for (int kk = 0; kk < 8; ++kk){
      short8 a = *(const short8*)&sQ[w*16 + cl][kk*32 + rowg*8];
#pragma unroll
      for (int nt = 0; nt < 4; ++nt){
        short8 bb = *(const short8*)&sK[nt*16 + cl][kk*32 + rowg*8];
        c[b][nt] = MFMA16(a, bb, c[b][nt]);
      }
    }
  }
  int lenv[8];
#pragma unroll
  for (int b = 0; b < 8; ++b) lenv[b] = lens[b];
  const int q0 = qt*64 + w*16 + rowg*4;
  float cs[8][4];
#pragma unroll
  for (int b = 0; b < 8; ++b)
#pragma unroll
    for (int nt = 0; nt < 4; ++nt) cs[b][nt] = 0.f;
#pragma unroll
  for (int nt = 0; nt < 4; ++nt){
#pragma unroll
    for (int r = 0; r < 4; ++r){
      float m = c[0][nt][r];
#pragma unroll
      for (int b = 1; b < 8; ++b) m = fmaxf(m, c[b][nt][r]);
      float e[8], s = 0.f;
#pragma unroll
      for (int b = 0; b < 8; ++b){ e[b] = __builtin_amdgcn_exp2f((c[b][nt][r] - m)*RSCALE_LG); s += e[b]; }
      float ri = __builtin_amdgcn_rcpf(s);
#pragma unroll
      for (int b = 0; b < 8; ++b)
        if (q0 + r < lenv[b]) cs[b][nt] += e[b]*ri;
    }
  }
#pragma unroll
  for (int b = 0; b < 8; ++b)
#pragma unroll
    for (int nt = 0; nt < 4; ++nt){
      float v = cs[b][nt];
      v += __shfl_xor(v, 16); v += __shfl_xor(v, 32);
      if (l < 16) atomicAdd(&cbuf[b][nt*16 + l], v);
    }
  __syncthreads();
  for (int i = tid; i < 512; i += 256)
    atomicAdd(&colsum[(size_t)(i >> 6)*2048 + kt*64 + (i & 63)], cbuf[i >> 6][i & 63]);
}

// ---------------- xg = in @ Wih^T, scaled/biased for exp2-based gates ----------------
template<int KIN>
__global__ __launch_bounds__(256, 1) void k_xg(const int* lens, char* ws){
  const int tt = blockIdx.x, b = blockIdx.y, dir = blockIdx.z;
  constexpr int LAYER = (KIN == 128) ? 0 : 1;
  const u16* in = (KIN == 128) ? (const u16*)(ws + OFS_PAD) : (const u16*)(ws + OFS_H1);
  const u16* wmat = ((KIN == 128) ? (const u16*)(ws + OFS_WIH0) : (const u16*)(ws + OFS_WIH1))
                    + (size_t)dir*384*KIN;
  const float* biasx = (const float*)(ws + OFS_BIASX) + (LAYER*2 + dir)*384;
  float* xg = (float*)(ws + OFS_XG) + (size_t)dir*2048*3072;
  const int lenb = lens[b];
  __shared__ __align__(16) u16 sA[64][KIN + 8];
  constexpr int CH = KIN/8;
  const int tid = threadIdx.x, w = tid >> 6, l = tid & 63, rowg = l >> 4, cl = l & 15;
  for (int idx = tid; idx < 64*CH; idx += 256){
    int row = idx / CH, chn = idx % CH;
    int t = tt*64 + row;
    int tr = dir ? ((t < lenb) ? (lenb - 1 - t) : t) : t;
    *(u16x8*)&sA[row][chn*8] = *(const u16x8*)(in + ((size_t)(b*2048 + tr))*KIN + chn*8);
  }
  __syncthreads();
  f32x4 acc[24];
#pragma unroll
  for (int nt = 0; nt < 24; ++nt) acc[nt] = f32x4{0.f,0.f,0.f,0.f};
#pragma unroll
  for (int kk = 0; kk < KIN/32; ++kk){
    short8 a = *(const short8*)&sA[w*16 + cl][kk*32 + rowg*8];
#pragma unroll
    for (int nt = 0; nt < 24; ++nt){
      short8 bb = *(const short8*)(wmat + (size_t)(nt*16 + cl)*KIN + kk*32 + rowg*8);
      acc[nt] = MFMA16(a, bb, acc[nt]);
    }
  }
#pragma unroll
  for (int nt = 0; nt < 24; ++nt){
    const int g = nt*16 + cl;
    const float bx = biasx[g];
    const float sc = (nt < 16) ? -LOG2E_C : TWOLOG2E_C;
#pragma unroll
    for (int r = 0; r < 4; ++r){
      const int t = tt*64 + w*16 + rowg*4 + r;
      xg[((size_t)t*8 + b)*384 + g] = sc*acc[nt][r] + bx;
    }
  }
}

// ---------------- GRU recurrence ----------------
// Layout notes:
//  - hb[cur] is a 16x128 bf16 tile: row16 = j>>3, col128 = c8*8 + (j&7), where
//    cols c8 in [0,8) hold batch c8 and cols [8,16) DUPLICATE batch c8-8 so that
//    every lane's MFMA C output holds both gate-tiles (p=0/1) for its own batch
//    => pe-select is a plain cndmask, no cross-lane shuffle.
//  - xg prefetch is a 4-deep register ring (named stages, fully unrolled),
//    issued right after the stage registers are consumed as MFMA C-init.
//  - h is NOT frozen past lens[b]: valid steps form a prefix, outputs past the
//    length are zeroed via ow cndmask, and h stays bounded (tanh/sigmoid).
__global__ __launch_bounds__(256, 1) void k_rec(const float* xg_all, const float* whh_all,
    const float* bhhn_all, const int* lens, u16* out)
{
  const int dir = blockIdx.x;
  const float* xg  = xg_all + (size_t)dir*2048*3072;
  const float* whh = whh_all + (size_t)dir*384*128;
  const float* bnd = bhhn_all + dir*128;
  const int tid = threadIdx.x;
  const int w = tid >> 6, l = tid & 63;
  const int rowg = l >> 4, cl = l & 15, b8 = l & 7, pe = (l >> 3) & 1;
  const bool peb = (pe != 0);
  const bool dirb = (dir != 0);
  __shared__ __align__(16) u16 hb[2][2048];
  for (int i = tid; i < 4096; i += 256) (&hb[0][0])[i] = 0;
  short8 aR[2][4], aZ[2][4], aN[2][4];
#pragma unroll
  for (int p = 0; p < 2; ++p){
#pragma unroll
    for (int kk = 0; kk < 4; ++kk){
      int k0 = kk*32 + rowg*8;
      aR[p][kk] = ld8cvt(whh + (size_t)((2*w + p)*16 + cl)*128 + k0, -LOG2E_C);
      aZ[p][kk] = ld8cvt(whh + (size_t)((8 + 2*w + p)*16 + cl)*128 + k0, -LOG2E_C);
      aN[p][kk] = ld8cvt(whh + (size_t)((16 + 2*w + p)*16 + cl)*128 + k0, TWOLOG2E_C);
    }
  }
  f32x4 bnU[2];
#pragma unroll
  for (int p = 0; p < 2; ++p)
#pragma unroll
    for (int r = 0; r < 4; ++r) bnU[p][r] = bnd[(2*w + p)*16 + rowg*4 + r];
  const int lenb = lens[b8];
  const int j0 = (2*w + pe)*16 + rowg*4;
  const int offR = b8*384 + 2*w*16 + rowg*4;   // floats; covers R p0/p1 and Z p0/p1 via +16/+128/+144
  const int offN = b8*384 + 256 + j0;          // floats; XN for this lane's gates
  const int hoff = ((j0 >> 3)*16 + b8)*8 + (j0 & 7);
  u16* outp = out + (size_t)b8*2048*256 + dir*128 + j0;
  float hp[4] = {0.f, 0.f, 0.f, 0.f};

#define LOAD_STAGE(T_, Ra, Rb, Za, Zb, Nv) do {            \
    const float* pb_ = xg + (size_t)(T_)*3072;             \
    Ra = *(const f32x4*)(pb_ + offR);                      \
    Rb = *(const f32x4*)(pb_ + offR + 16);                 \
    Za = *(const f32x4*)(pb_ + offR + 128);                \
    Zb = *(const f32x4*)(pb_ + offR + 144);                \
    Nv = *(const f32x4*)(pb_ + offN);                      \
  } while (0)

#define REC_STEP(T_, PF_, CUR_, Ra, Rb, Za, Zb, Nv) do {                              \
    short8 bf0_ = *(const short8*)(&hb[CUR_][0] + (size_t)((0*4 + rowg)*128 + cl*8)); \
    short8 bf1_ = *(const short8*)(&hb[CUR_][0] + (size_t)((1*4 + rowg)*128 + cl*8)); \
    short8 bf2_ = *(const short8*)(&hb[CUR_][0] + (size_t)((2*4 + rowg)*128 + cl*8)); \
    short8 bf3_ = *(const short8*)(&hb[CUR_][0] + (size_t)((3*4 + rowg)*128 + cl*8)); \
    f32x4 cR0_ = MFMA16(aR[0][0], bf0_, Ra);                                          \
    f32x4 cR1_ = MFMA16(aR[1][0], bf0_, Rb);                                          \
    f32x4 cZ0_ = MFMA16(aZ[0][0], bf0_, Za);                                          \
    f32x4 cZ1_ = MFMA16(aZ[1][0], bf0_, Zb);                                          \
    f32x4 cN0_ = MFMA16(aN[0][0], bf0_, bnU[0]);                                      \
    f32x4 cN1_ = MFMA16(aN[1][0], bf0_, bnU[1]);                                      \
    cR0_ = MFMA16(aR[0][1], bf1_, cR0_);  cR1_ = MFMA16(aR[1][1], bf1_, cR1_);        \
    cZ0_ = MFMA16(aZ[0][1], bf1_, cZ0_);  cZ1_ = MFMA16(aZ[1][1], bf1_, cZ1_);        \
    cN0_ = MFMA16(aN[0][1], bf1_, cN0_);  cN1_ = MFMA16(aN[1][1], bf1_, cN1_);        \
    cR0_ = MFMA16(aR[0][2], bf2_, cR0_);  cR1_ = MFMA16(aR[1][2], bf2_, cR1_);        \
    cZ0_ = MFMA16(aZ[0][2], bf2_, cZ0_);  cZ1_ = MFMA16(aZ[1][2], bf2_, cZ1_);        \
    cN0_ = MFMA16(aN[0][2], bf2_, cN0_);  cN1_ = MFMA16(aN[1][2], bf2_, cN1_);        \
    cR0_ = MFMA16(aR[0][3], bf3_, cR0_);  cR1_ = MFMA16(aR[1][3], bf3_, cR1_);        \
    cZ0_ = MFMA16(aZ[0][3], bf3_, cZ0_);  cZ1_ = MFMA16(aZ[1][3], bf3_, cZ1_);        \
    cN0_ = MFMA16(aN[0][3], bf3_, cN0_);  cN1_ = MFMA16(aN[1][3], bf3_, cN1_);        \
    const float* pfb_ = xg + (size_t)(PF_)*3072;                                      \
    Ra = *(const f32x4*)(pfb_ + offR);                                                \
    Rb = *(const f32x4*)(pfb_ + offR + 16);                                           \
    Za = *(const f32x4*)(pfb_ + offR + 128);                                          \
    Zb = *(const f32x4*)(pfb_ + offR + 144);                                          \
    const bool v_ = (T_) < lenb;                                                      \
    float hn_[4];                                                                     \
    _Pragma("unroll")                                                                 \
    for (int r = 0; r < 4; ++r){                                                      \
      float gR = peb ? cR1_[r] : cR0_[r];                                             \
      float gZ = peb ? cZ1_[r] : cZ0_[r];                                             \
      float gN = peb ? cN1_[r] : cN0_[r];                                             \
      float Rg = __builtin_amdgcn_rcpf(1.f + __builtin_amdgcn_exp2f(gR));             \
      float Zg = __builtin_amdgcn_rcpf(1.f + __builtin_amdgcn_exp2f(gZ));             \
      float y  = Nv[r] + Rg*gN;                                                       \
      float NN = 1.f - 2.f*__builtin_amdgcn_rcpf(1.f + __builtin_amdgcn_exp2f(y));    \
      float hn = NN + Zg*(hp[r] - NN);                                                \
      hp[r] = hn; hn_[r] = hn;                                                        \
    }                                                                                 \
    u32 hw0_ = cvtpk(hn_[0], hn_[1]);                                                 \
    u32 hw1_ = cvtpk(hn_[2], hn_[3]);                                                 \
    u32 ow0_ = v_ ? hw0_ : 0u;                                                        \
    u32 ow1_ = v_ ? hw1_ : 0u;                                                        \
    Nv = *(const f32x4*)(pfb_ + offN);                                                \
    u16* hd_ = &hb[(CUR_) ^ 1][0] + hoff;                                             \
    *(u32x2*)hd_ = u32x2{hw0_, hw1_};                                                 \
    *(u32x2*)(hd_ + 64) = u32x2{hw0_, hw1_};                                          \
    int to_ = dirb ? (v_ ? (lenb - 1 - (T_)) : (T_)) : (T_);                          \
    *(u32x2*)(outp + (size_t)to_*256) = u32x2{ow0_, ow1_};                            \
    asm volatile("s_waitcnt lgkmcnt(0)" ::: "memory");                                \
    __builtin_amdgcn_s_barrier();                                                     \
  } while (0)

  f32x4 R0a, R0b, Z0a, Z0b, N0v;
  f32x4 R1a, R1b, Z1a, Z1b, N1v;
  f32x4 R2a, R2b, Z2a, Z2b, N2v;
  f32x4 R3a, R3b, Z3a, Z3b, N3v;
  __syncthreads();
  LOAD_STAGE(0, R0a, R0b, Z0a, Z0b, N0v);
  LOAD_STAGE(1, R1a, R1b, Z1a, Z1b, N1v);
  LOAD_STAGE(2, R2a, R2b, Z2a, Z2b, N2v);
  LOAD_STAGE(3, R3a, R3b, Z3a, Z3b, N3v);
  for (int t = 0; t < 2048; t += 4){
    int p4 = (t + 4 < 2048) ? (t + 4) : 2047;
    int p5 = (t + 5 < 2048) ? (t + 5) : 2047;
    int p6 = (t + 6 < 2048) ? (t + 6) : 2047;
    int p7 = (t + 7 < 2048) ? (t + 7) : 2047;
    REC_STEP(t + 0, p4, 0, R0a, R0b, Z0a, Z0b, N0v);
    REC_STEP(t + 1, p5, 1, R1a, R1b, Z1a, Z1b, N1v);
    REC_STEP(t + 2, p6, 0, R2a, R2b, Z2a, Z2b, N2v);
    REC_STEP(t + 3, p7, 1, R3a, R3b, Z3a, Z3b, N3v);
  }
#undef LOAD_STAGE
#undef REC_STEP
}

// ---------------- encW = enc @ Wa2^T ----------------
__global__ __launch_bounds__(256, 1) void k_encw(char* ws){
  const int tt = blockIdx.x, b = blockIdx.y;
  const u16* in = (const u16*)(ws + OFS_ENC);
  const u16* wmat = (const u16*)(ws + OFS_WA2);
  float* out = (float*)(ws + OFS_ENCW);
  __shared__ __align__(16) u16 sA[64][264];
  const int tid = threadIdx.x, w = tid >> 6, l = tid & 63, rowg = l >> 4, cl = l & 15;
  for (int idx = tid; idx < 64*32; idx += 256){
    int row = idx >> 5, chn = idx & 31;
    int t = tt*64 + row;
    *(u16x8*)&sA[row][chn*8] = *(const u16x8*)(in + ((size_t)(b*2048 + t))*256 + chn*8);
  }
  __syncthreads();
  f32x4 acc[16];
#pragma unroll
  for (int nt = 0; nt < 16; ++nt) acc[nt] = f32x4{0.f,0.f,0.f,0.f};
#pragma unroll
  for (int kk = 0; kk < 8; ++kk){
    short8 a = *(const short8*)&sA[w*16 + cl][kk*32 + rowg*8];
#pragma unroll
    for (int nt = 0; nt < 16; ++nt){
      short8 bb = *(const short8*)(wmat + (size_t)(nt*16 + cl)*256 + kk*32 + rowg*8);
      acc[nt] = MFMA16(a, bb, acc[nt]);
    }
  }
#pragma unroll
  for (int nt = 0; nt < 16; ++nt){
    int h = nt*16 + cl;
#pragma unroll
    for (int r = 0; r < 4; ++r){
      int t = tt*64 + w*16 + rowg*4 + r;
      out[((size_t)(b*2048 + t))*256 + h] = acc[nt][r];
    }
  }
}

// ---------------- sa[b][d] = sum_k colsum[b][k] * V[b][k][d] ----------------
__global__ __launch_bounds__(256) void k_sa(char* ws){
  const int b = blockIdx.x, d = threadIdx.x;
  const float* cs = (const float*)(ws + OFS_CS) + (size_t)b*2048;
  const u16* V = (const u16*)(ws + OFS_V) + (size_t)b*2048*256;
  float a0 = 0.f, a1 = 0.f, a2 = 0.f, a3 = 0.f;
  for (int k = 0; k < 2048; k += 4){
    a0 += cs[k + 0]*bf2f(V[(size_t)(k + 0)*256 + d]);
    a1 += cs[k + 1]*bf2f(V[(size_t)(k + 1)*256 + d]);
    a2 += cs[k + 2]*bf2f(V[(size_t)(k + 2)*256 + d]);
    a3 += cs[k + 3]*bf2f(V[(size_t)(k + 3)*256 + d]);
  }
  ((float*)(ws + OFS_SA))[b*256 + d] = (a0 + a1) + (a2 + a3);
}

// ---------------- additive-attn scores (pre-softmax, masked) ----------------
__global__ __launch_bounds__(256) void k_res(const int* lens, const float* WaW, const float* Wab,
    const float* VTw, const float* VTb, char* ws){
  const int b = blockIdx.x, x = blockIdx.y, chb = blockIdx.z;
  const float* tm = (const float*)(ws + OFS_TM) + b*128;
  const float* sa = (const float*)(ws + OFS_SA) + b*256;
  const float* encW = (const float*)(ws + OFS_ENCW);
  float* res = (float*)(ws + OFS_RES) + ((size_t)b*2 + x)*2048;
  __shared__ float sw[256];
  __shared__ float vt[256];
  const int tid = threadIdx.x;
  {
    int h = tid;
    float acc = Wab[h];
    if (x == 0){
      for (int j = 0; j < 128; ++j)
        acc += tm[j]*(1.f/2048.f)*(WaW[(size_t)h*512 + 2*j] + WaW[(size_t)h*512 + 2*j + 1]);
    } else {
      for (int k = 0; k < 256; ++k) acc += sa[k]*WaW[(size_t)h*512 + k];
    }
    sw[h] = acc;
    vt[h] = VTw[h];
  }
  __syncthreads();
  const int lenb = lens[b];
  const int lsub = tid >> 2, q = tid & 3;
  const float vtb = VTb[0];
#pragma unroll
  for (int pass = 0; pass < 4; ++pass){
    const int ll = chb*256 + pass*64 + lsub;
    const float* er = encW + ((size_t)(b*2048 + ll))*256 + q*64;
    float racc = 0.f;
    for (int j = 0; j < 64; ++j){
      float u = er[j] + sw[q*64 + j];
      float th = 1.f - 2.f*__builtin_amdgcn_rcpf(1.f + __builtin_amdgcn_exp2f(u*TWOLOG2E_C));
      racc += th*vt[q*64 + j];
    }
    racc += __shfl_xor(racc, 1);
    racc += __shfl_xor(racc, 2);
    if (q == 0) res[ll] = (ll < lenb) ? (racc + vtb) : 0.f;
  }
}

// ---------------- softmax over L + weighted enc sum → d1/d2 ----------------
__global__ __launch_bounds__(256) void k_attnfin(char* ws){
  const int b = blockIdx.x, x = blockIdx.y;
  const float* res = (const float*)(ws + OFS_RES) + ((size_t)b*2 + x)*2048;
  const u16* enc = (const u16*)(ws + OFS_ENC);
  float* dvec = (float*)(ws + OFS_DV);
  __shared__ float sv[2048];
  __shared__ float red[8];
  const int tid = threadIdx.x;
  float m = -3.0e38f;
  for (int i = tid; i < 2048; i += 256){ float v = res[i]; sv[i] = v; m = fmaxf(m, v); }
#pragma unroll
  for (int o = 1; o < 64; o <<= 1) m = fmaxf(m, __shfl_xor(m, o));
  if ((tid & 63) == 0) red[tid >> 6] = m;
  __syncthreads();
  m = fmaxf(fmaxf(red[0], red[1]), fmaxf(red[2], red[3]));
  __syncthreads();
  float s = 0.f;
  for (int i = tid; i < 2048; i += 256){ float e = __builtin_amdgcn_exp2f((sv[i] - m)*LOG2E_C); sv[i] = e; s += e; }
#pragma unroll
  for (int o = 1; o < 64; o <<= 1) s += __shfl_xor(s, o);
  if ((tid & 63) == 0) red[tid >> 6] = s;
  __syncthreads();
  const float S = red[0] + red[1] + red[2] + red[3];
  const float ri = 1.0f/S;
  const int h = tid;
  float a0 = 0.f, a1 = 0.f, a2 = 0.f, a3 = 0.f;
  for (int l0 = 0; l0 < 2048; l0 += 4){
    a0 += sv[l0 + 0]*bf2f(enc[((size_t)(b*2048 + l0 + 0))*256 + h]);
    a1 += sv[l0 + 1]*bf2f(enc[((size_t)(b*2048 + l0 + 1))*256 + h]);
    a2 += sv[l0 + 2]*bf2f(enc[((size_t)(b*2048 + l0 + 2))*256 + h]);
    a3 += sv[l0 + 3]*bf2f(enc[((size_t)(b*2048 + l0 + 3))*256 + h]);
  }
  dvec[((size_t)b*2 + x)*256 + h] = ((a0 + a1) + (a2 + a3))*ri;
}

// ---------------- final FC ----------------
__global__ __launch_bounds__(64) void k_final(const float* fcw, const float* fcb, char* ws, float* outp){
  const int i = threadIdx.x;
  if (i >= 48) return;
  const int b = i/6, o = i%6;
  const float* dv = (const float*)(ws + OFS_DV);
  float acc = fcb[o];
  for (int h = 0; h < 256; ++h)
    acc += 0.5f*(dv[((size_t)b*2 + 0)*256 + h] + dv[((size_t)b*2 + 1)*256 + h])*fcw[o*256 + h];
  outp[i] = acc;
}

// ---------------- host ----------------
extern "C" void kernel_launch(void* const* d_in, const int* in_sizes, int n_in,
                              void* d_out, int out_size, void* d_ws, size_t ws_size,
                              hipStream_t stream)
{
  const int* tok    = (const int*)d_in[0];
  const int* lens   = (const int*)d_in[1];
  const float* embed= (const float*)d_in[2];
  const float* wih0 = (const float*)d_in[3];
  const float* whh0 = (const float*)d_in[4];
  const float* bih0 = (const float*)d_in[5];
  const float* bhh0 = (const float*)d_in[6];
  const float* wih1 = (const float*)d_in[7];
  const float* whh1 = (const float*)d_in[8];
  const float* bih1 = (const float*)d_in[9];
  const float* bhh1 = (const float*)d_in[10];
  const float* convw= (const float*)d_in[11];
  const float* convb= (const float*)d_in[12];
  const float* WaW  = (const float*)d_in[13];
  const float* Wab  = (const float*)d_in[14];
  const float* VTw  = (const float*)d_in[15];
  const float* VTb  = (const float*)d_in[16];
  const float* Qw   = (const float*)d_in[17];
  const float* Kw   = (const float*)d_in[18];
  const float* Vw   = (const float*)d_in[19];
  const float* fcw  = (const float*)d_in[20];
  const float* fcb  = (const float*)d_in[21];
  char* ws = (char*)d_ws;
  float* outp = (float*)d_out;

  hipLaunchKernelGGL(k_prep, dim3(2048), dim3(256), 0, stream,
      tok, lens, embed, wih0, wih1, bih0, bhh0, bih1, bhh1, convw, WaW, Qw, Kw, Vw, ws);
  hipLaunchKernelGGL((k_conv<2051,2050,0>), dim3(33,8), dim3(256), 0, stream, lens, convb, ws);
  hipLaunchKernelGGL((k_conv<2050,2049,1>), dim3(33,8), dim3(256), 0, stream, lens, convb, ws);
  hipLaunchKernelGGL((k_conv<2049,2048,2>), dim3(32,8), dim3(256), 0, stream, lens, convb, ws);
  hipLaunchKernelGGL(k_qkv, dim3(32,8,3), dim3(256), 0, stream, ws);
  hipLaunchKernelGGL(k_scores, dim3(32,32), dim3(256), 0, stream, lens, ws);
  hipLaunchKernelGGL((k_xg<128>), dim3(32,8,2), dim3(256), 0, stream, lens, ws);
  hipLaunchKernelGGL(k_rec, dim3(2), dim3(256), 0, stream,
      (const float*)(ws + OFS_XG), whh0, (const float*)(ws + OFS_BHHN), lens, (u16*)(ws + OFS_H1));
  hipLaunchKernelGGL((k_xg<256>), dim3(32,8,2), dim3(256), 0, stream, lens, ws);
  hipLaunchKernelGGL(k_rec, dim3(2), dim3(256), 0, stream,
      (const float*)(ws + OFS_XG), whh1, (const float*)(ws + OFS_BHHN) + 2*128, lens, (u16*)(ws + OFS_ENC));
  hipLaunchKernelGGL(k_encw, dim3(32,8), dim3(256), 0, stream, ws);
  hipLaunchKernelGGL(k_sa, dim3(8), dim3(256), 0, stream, ws);
  hipLaunchKernelGGL(k_res, dim3(8,2,8), dim3(256), 0, stream, lens, WaW, Wab, VTw, VTb, ws);
  hipLaunchKernelGGL(k_attnfin, dim3(8,2), dim3(256), 0, stream, ws);
  hipLaunchKernelGGL(k_final, dim3(1), dim3(64), 0, stream, fcw, fcb, ws, outp);
  (void)in_sizes; (void)n_in; (void)out_size; (void)ws_size;
}